// Round 10
// baseline (3017.186 us; speedup 1.0000x reference)
//
#include <hip/hip_runtime.h>

#define L_SEQ 512
#define B_SZ  1024
#define HD    64
#define XROW  152                       // sXH row stride (floats)
#define XIDX(k) ((k) + 8 * ((k) >> 5))  // +8 words per 32-block: kc-groups hit disjoint banks

__device__ __forceinline__ float fast_sigmoid(float x) {
    return __builtin_amdgcn_rcpf(1.0f + __builtin_amdgcn_exp2f(-1.4426950408889634f * x));
}
__device__ __forceinline__ float fast_tanh(float x) {
    return 1.0f - 2.0f * __builtin_amdgcn_rcpf(1.0f + __builtin_amdgcn_exp2f(2.8853900817779268f * x));
}
#define PIN(x) asm volatile("" : "+v"(x))

// 256 blocks x 1024 threads (16 waves). Block = 1 CU = 4 batch rows, all 512 steps.
// Wave w: gate = w>>2 (0=z, 1=r, 2=cand-x, 3=cand-rh), c = w&3 = col-chunk = SIMD id
// -> each SIMD hosts one wave of every gate (phase A co-issues z+r+cx).
// Lane = (jj = lane&15 -> col j = 16c+jj, kc = lane>>4 -> k-slice of 32).
// Weights: 32 (z/r) or 16 (cand) floats per thread in REGISTERS, loaded once.
// k-partials reduced in-wave via 2x shfl_xor -> no LDS partial buffers.
// 2 barriers/step. cand-rh waves prefetch next-step embeddings during phase A.
__global__ __launch_bounds__(1024, 4) void gru_fused_kernel(
    const int* __restrict__ xind, const float* __restrict__ emb,
    const float* __restrict__ Wz, const float* __restrict__ Wr,
    const float* __restrict__ Wh, float* __restrict__ out)
{
    __shared__ __align__(16) float sXH[4 * XROW];  // [b][ x(0..63) | h(64..127) ] swizzled
    __shared__ __align__(16) float sRH[4 * 64];    // r*h
    __shared__ __align__(16) float sZ [4 * 64];    // z
    __shared__ __align__(16) float sCX[4 * 64];    // cand x-part dot

    const int tid  = threadIdx.x;
    const int lane = tid & 63;
    const int w    = tid >> 6;      // 0..15
    const int gate = w >> 2;        // 0=z 1=r 2=cx 3=ch
    const int c    = w & 3;         // col chunk == SIMD id
    const int jj   = lane & 15;
    const int kc   = lane >> 4;     // 0..3
    const int j    = c * 16 + jj;
    const int row0 = blockIdx.x * 4;

    // ---- weights -> registers (one-time). Wz/Wr rows: 0..63 x, 64..127 h.
    // Wh rows: 0..63 multiply r*h, 64..127 multiply x. ----
    float wreg[32];
    if (gate < 2) {
        const float* W = (gate == 0) ? Wz : Wr;
#pragma unroll
        for (int i = 0; i < 32; ++i) wreg[i] = W[(32 * kc + i) * 64 + j];
#pragma unroll
        for (int i = 0; i < 32; ++i) PIN(wreg[i]);
    } else if (gate == 2) {
#pragma unroll
        for (int i = 0; i < 16; ++i) wreg[i] = Wh[(64 + 16 * kc + i) * 64 + j];
#pragma unroll
        for (int i = 0; i < 16; ++i) PIN(wreg[i]);
    } else {
#pragma unroll
        for (int i = 0; i < 16; ++i) wreg[i] = Wh[(16 * kc + i) * 64 + j];
#pragma unroll
        for (int i = 0; i < 16; ++i) PIN(wreg[i]);
    }

    // ---- init: h = 0 (z waves), x(0) (ch waves) ----
    if (gate == 0) {
        sXH[c * XROW + XIDX(64 + lane)] = 0.0f;
    } else if (gate == 3) {
        sXH[c * XROW + XIDX(lane)] = emb[(size_t)xind[row0 + c] * HD + lane];
    }
    int idxn = (gate == 3) ? xind[B_SZ + row0 + c] : 0;   // index for t=1
    __syncthreads();

    for (int t = 0; t < L_SEQ; ++t) {
        // ================= Phase A =================
        if (gate < 2) {
            // z / r: full 128-k dot; this lane covers k in [32kc, 32kc+32)
            float acc[4] = {0.f, 0.f, 0.f, 0.f};
            const int xb = 40 * kc;                 // XIDX(32*kc)
#pragma unroll
            for (int q = 0; q < 8; ++q) {
#pragma unroll
                for (int b = 0; b < 4; ++b) {
                    const float4 xq = *(const float4*)&sXH[b * XROW + xb + 4 * q];
                    acc[b] = fmaf(wreg[4 * q + 0], xq.x, acc[b]);
                    acc[b] = fmaf(wreg[4 * q + 1], xq.y, acc[b]);
                    acc[b] = fmaf(wreg[4 * q + 2], xq.z, acc[b]);
                    acc[b] = fmaf(wreg[4 * q + 3], xq.w, acc[b]);
                }
            }
#pragma unroll
            for (int b = 0; b < 4; ++b) {
                float v = acc[b];
                v += __shfl_xor(v, 16);
                v += __shfl_xor(v, 32);
                const float g = fast_sigmoid(v);
                if (gate == 0) {
                    if (kc == 0) sZ[b * 64 + j] = g;
                } else {
                    if (kc == 0) sRH[b * 64 + j] = g * sXH[b * XROW + XIDX(64 + j)];
                }
            }
        } else if (gate == 2) {
            // cand-x: k in [64+16kc, 64+16kc+16) pairs with x[16kc..16kc+16)
            float acc[4] = {0.f, 0.f, 0.f, 0.f};
            const int xb = 16 * kc + 8 * (kc >> 1); // XIDX(16*kc)
#pragma unroll
            for (int q = 0; q < 4; ++q) {
#pragma unroll
                for (int b = 0; b < 4; ++b) {
                    const float4 xq = *(const float4*)&sXH[b * XROW + xb + 4 * q];
                    acc[b] = fmaf(wreg[4 * q + 0], xq.x, acc[b]);
                    acc[b] = fmaf(wreg[4 * q + 1], xq.y, acc[b]);
                    acc[b] = fmaf(wreg[4 * q + 2], xq.z, acc[b]);
                    acc[b] = fmaf(wreg[4 * q + 3], xq.w, acc[b]);
                }
            }
#pragma unroll
            for (int b = 0; b < 4; ++b) {
                float v = acc[b];
                v += __shfl_xor(v, 16);
                v += __shfl_xor(v, 32);
                if (kc == 0) sCX[b * 64 + j] = v;
            }
        }
        // ch waves: prefetch next-step embedding row + index (under phase A)
        float ev = 0.0f;
        if (gate == 3) {
            if (t < L_SEQ - 1) ev = emb[(size_t)idxn * HD + lane];
            if (t < L_SEQ - 2) idxn = xind[(size_t)(t + 2) * B_SZ + row0 + c];
        }
        __syncthreads();

        // ================= Phase B (cand-rh waves only) =================
        if (gate == 3) {
            float acc[4] = {0.f, 0.f, 0.f, 0.f};
#pragma unroll
            for (int q = 0; q < 4; ++q) {
#pragma unroll
                for (int b = 0; b < 4; ++b) {
                    const float4 rq = *(const float4*)&sRH[b * 64 + 16 * kc + 4 * q];
                    acc[b] = fmaf(wreg[4 * q + 0], rq.x, acc[b]);
                    acc[b] = fmaf(wreg[4 * q + 1], rq.y, acc[b]);
                    acc[b] = fmaf(wreg[4 * q + 2], rq.z, acc[b]);
                    acc[b] = fmaf(wreg[4 * q + 3], rq.w, acc[b]);
                }
            }
#pragma unroll
            for (int b = 0; b < 4; ++b) {
                float v = acc[b];
                v += __shfl_xor(v, 16);
                v += __shfl_xor(v, 32);
                const float s  = v + sCX[b * 64 + j];
                const float hc = fast_tanh(s);
                const float z  = sZ[b * 64 + j];
                const float ho = sXH[b * XROW + XIDX(64 + j)];
                const float hn = fmaf(z, hc - ho, ho);
                if (kc == 0) {
                    sXH[b * XROW + XIDX(64 + j)] = hn;
                    out[(size_t)t * (B_SZ * HD) + (size_t)(row0 + b) * HD + j] = hn;
                    if (t == L_SEQ - 1)
                        out[(size_t)L_SEQ * (B_SZ * HD) + (size_t)(row0 + b) * HD + j] = hn;
                }
            }
            if (t < L_SEQ - 1) sXH[c * XROW + XIDX(lane)] = ev;  // commit x(t+1)
        }
        __syncthreads();
    }
}

extern "C" void kernel_launch(void* const* d_in, const int* in_sizes, int n_in,
                              void* d_out, int out_size, void* d_ws, size_t ws_size,
                              hipStream_t stream) {
    (void)in_sizes; (void)n_in; (void)out_size; (void)d_ws; (void)ws_size;
    const int*   x   = (const int*)  d_in[0];
    const float* emb = (const float*)d_in[1];
    const float* Wz  = (const float*)d_in[2];
    const float* Wr  = (const float*)d_in[3];
    const float* Wh  = (const float*)d_in[4];
    float* out = (float*)d_out;

    gru_fused_kernel<<<dim3(B_SZ / 4), dim3(1024), 0, stream>>>(x, emb, Wz, Wr, Wh, out);
}